// Round 1
// baseline (2034.815 us; speedup 1.0000x reference)
//
#include <hip/hip_runtime.h>
#include <hip/hip_bf16.h>

#define DIM 32

// One edge per 32-lane group; lane d handles dimension d.
// Gather e_cur[col] (coalesced 128B), scale by val, atomic scatter to e_next[row].
__global__ void lgcn_scatter(const float* __restrict__ e_cur,
                             float* __restrict__ e_next,
                             const float* __restrict__ vals,
                             const int* __restrict__ row_idx,
                             const int* __restrict__ col_idx,
                             int E) {
    int g = blockIdx.x * (blockDim.x >> 5) + (threadIdx.x >> 5);
    if (g >= E) return;
    int d = threadIdx.x & 31;
    int c = col_idx[g];
    int r = row_idx[g];
    float v = vals[g];
    float m = v * e_cur[(size_t)c * DIM + d];
    atomicAdd(&e_next[(size_t)r * DIM + d], m);
}

// out = a + b   (float4-vectorized)
__global__ void lgcn_add_init(const float* __restrict__ a,
                              const float* __restrict__ b,
                              float* __restrict__ out, int n4) {
    int i = blockIdx.x * blockDim.x + threadIdx.x;
    if (i >= n4) return;
    float4 x = ((const float4*)a)[i];
    float4 y = ((const float4*)b)[i];
    ((float4*)out)[i] = make_float4(x.x + y.x, x.y + y.y, x.z + y.z, x.w + y.w);
}

// out += b
__global__ void lgcn_add(const float* __restrict__ b,
                         float* __restrict__ out, int n4) {
    int i = blockIdx.x * blockDim.x + threadIdx.x;
    if (i >= n4) return;
    float4 x = ((float4*)out)[i];
    float4 y = ((const float4*)b)[i];
    ((float4*)out)[i] = make_float4(x.x + y.x, x.y + y.y, x.z + y.z, x.w + y.w);
}

// out = (out + b) * s
__global__ void lgcn_add_scale(const float* __restrict__ b,
                               float* __restrict__ out, int n4, float s) {
    int i = blockIdx.x * blockDim.x + threadIdx.x;
    if (i >= n4) return;
    float4 x = ((float4*)out)[i];
    float4 y = ((const float4*)b)[i];
    ((float4*)out)[i] = make_float4((x.x + y.x) * s, (x.y + y.y) * s,
                                    (x.z + y.z) * s, (x.w + y.w) * s);
}

extern "C" void kernel_launch(void* const* d_in, const int* in_sizes, int n_in,
                              void* d_out, int out_size, void* d_ws, size_t ws_size,
                              hipStream_t stream) {
    const float* emb  = (const float*)d_in[0];
    const float* vals = (const float*)d_in[1];
    const int*   row  = (const int*)d_in[2];
    const int*   col  = (const int*)d_in[3];
    // num_layers (d_in[4]) is a device scalar; fixed at 3 in the reference.

    const int N = in_sizes[0] / DIM;     // 200000
    const int E = in_sizes[1];           // 6.4M
    float* out  = (float*)d_out;

    float* bufA = (float*)d_ws;
    float* bufB = bufA + (size_t)N * DIM;
    const size_t layer_bytes = (size_t)N * DIM * sizeof(float);

    const int SCT_BLK = 256;                      // 8 edges per block
    const int sct_grid = (E + 7) / 8;
    const int n4 = N * DIM / 4;
    const int ADD_BLK = 256;
    const int add_grid = (n4 + ADD_BLK - 1) / ADD_BLK;

    // layer 1: e1 = A @ e0 (e0 = embedding, read in place)
    hipMemsetAsync(bufA, 0, layer_bytes, stream);
    lgcn_scatter<<<sct_grid, SCT_BLK, 0, stream>>>(emb, bufA, vals, row, col, E);
    lgcn_add_init<<<add_grid, ADD_BLK, 0, stream>>>(emb, bufA, out, n4);  // out = e0 + e1

    // layer 2: e2 = A @ e1
    hipMemsetAsync(bufB, 0, layer_bytes, stream);
    lgcn_scatter<<<sct_grid, SCT_BLK, 0, stream>>>(bufA, bufB, vals, row, col, E);
    lgcn_add<<<add_grid, ADD_BLK, 0, stream>>>(bufB, out, n4);            // out += e2

    // layer 3: e3 = A @ e2  (bufA reusable now)
    hipMemsetAsync(bufA, 0, layer_bytes, stream);
    lgcn_scatter<<<sct_grid, SCT_BLK, 0, stream>>>(bufB, bufA, vals, row, col, E);
    lgcn_add_scale<<<add_grid, ADD_BLK, 0, stream>>>(bufA, out, n4, 0.25f); // out = (out+e3)/4
}

// Round 3
// 1651.831 us; speedup vs baseline: 1.2319x; 1.2319x over previous
//
#include <hip/hip_runtime.h>
#include <hip/hip_bf16.h>

#define DIM 32

// ---------------- CSR build ----------------

__global__ void lgcn_hist(const int* __restrict__ row_idx,
                          int* __restrict__ count, int E) {
    int i = blockIdx.x * blockDim.x + threadIdx.x;
    if (i < E) atomicAdd(&count[row_idx[i]], 1);
}

// Exclusive scan: row_ptr[i] = sum(count[0..i)) for i in [0,n). Single block, 1024 thr.
__global__ void lgcn_scan(const int* __restrict__ count,
                          int* __restrict__ row_ptr, int n) {
    __shared__ int sums[1024];
    int t = threadIdx.x;
    int per = (n + 1023) >> 10;
    int start = t * per;
    int end = start + per < n ? start + per : n;
    int s = 0;
    for (int i = start; i < end; ++i) s += count[i];
    sums[t] = s;
    __syncthreads();
    for (int off = 1; off < 1024; off <<= 1) {
        int v = (t >= off) ? sums[t - off] : 0;
        __syncthreads();
        sums[t] += v;
        __syncthreads();
    }
    int base = (t == 0) ? 0 : sums[t - 1];
    for (int i = start; i < end; ++i) {
        row_ptr[i] = base;
        base += count[i];
    }
}

// Scatter (col,val) pairs into CSR slots. DESTRUCTIVELY advances cursor:
// after this kernel, cursor[r] == end-of-row-r offset (== start of row r+1).
__global__ void lgcn_permute(const int* __restrict__ row_idx,
                             const int* __restrict__ col_idx,
                             const float* __restrict__ vals,
                             int* __restrict__ cursor,
                             int2* __restrict__ perm, int E) {
    int i = blockIdx.x * blockDim.x + threadIdx.x;
    if (i >= E) return;
    int r = row_idx[i];
    int p = atomicAdd(&cursor[r], 1);
    perm[p] = make_int2(col_idx[i], __float_as_int(vals[i]));
}

// ---------------- pull SpMM, fused layer-sum epilogue ----------------
// row_end[r] = end offset of row r (post-permute row_ptr); beg = row_end[r-1].
// MODE 0: e_next = acc; out = emb + acc            (layer 1)
// MODE 1: e_next = acc; out += acc                 (layer 2)
// MODE 2: out = (out + acc) * 0.25                 (layer 3)
template <int MODE>
__global__ void lgcn_pull(const int* __restrict__ row_end,
                          const int2* __restrict__ perm,
                          const float* __restrict__ e_cur,
                          float* __restrict__ e_next,
                          const float* __restrict__ emb,
                          float* __restrict__ out, int N) {
    int g = blockIdx.x * (blockDim.x >> 5) + (threadIdx.x >> 5);
    if (g >= N) return;
    int d = threadIdx.x & 31;
    int beg = (g == 0) ? 0 : row_end[g - 1];
    int end = row_end[g];
    float acc = 0.f;
    int p = beg;
    for (; p + 1 < end; p += 2) {
        int2 cv0 = perm[p];
        int2 cv1 = perm[p + 1];
        acc = fmaf(__int_as_float(cv0.y), e_cur[(size_t)cv0.x * DIM + d], acc);
        acc = fmaf(__int_as_float(cv1.y), e_cur[(size_t)cv1.x * DIM + d], acc);
    }
    if (p < end) {
        int2 cv = perm[p];
        acc = fmaf(__int_as_float(cv.y), e_cur[(size_t)cv.x * DIM + d], acc);
    }
    size_t o = (size_t)g * DIM + d;
    if (MODE == 0)      { e_next[o] = acc; out[o] = emb[o] + acc; }
    else if (MODE == 1) { e_next[o] = acc; out[o] += acc; }
    else                { out[o] = (out[o] + acc) * 0.25f; }
}

// ---------------- fallback (round-1 verified atomic path) ----------------

__global__ void lgcn_scatter(const float* __restrict__ e_cur,
                             float* __restrict__ e_next,
                             const float* __restrict__ vals,
                             const int* __restrict__ row_idx,
                             const int* __restrict__ col_idx, int E) {
    int g = blockIdx.x * (blockDim.x >> 5) + (threadIdx.x >> 5);
    if (g >= E) return;
    int d = threadIdx.x & 31;
    int c = col_idx[g];
    int r = row_idx[g];
    float v = vals[g];
    atomicAdd(&e_next[(size_t)r * DIM + d], v * e_cur[(size_t)c * DIM + d]);
}

__global__ void lgcn_add_init(const float* __restrict__ a, const float* __restrict__ b,
                              float* __restrict__ out, int n4) {
    int i = blockIdx.x * blockDim.x + threadIdx.x;
    if (i >= n4) return;
    float4 x = ((const float4*)a)[i]; float4 y = ((const float4*)b)[i];
    ((float4*)out)[i] = make_float4(x.x + y.x, x.y + y.y, x.z + y.z, x.w + y.w);
}
__global__ void lgcn_add(const float* __restrict__ b, float* __restrict__ out, int n4) {
    int i = blockIdx.x * blockDim.x + threadIdx.x;
    if (i >= n4) return;
    float4 x = ((float4*)out)[i]; float4 y = ((const float4*)b)[i];
    ((float4*)out)[i] = make_float4(x.x + y.x, x.y + y.y, x.z + y.z, x.w + y.w);
}
__global__ void lgcn_add_scale(const float* __restrict__ b, float* __restrict__ out,
                               int n4, float s) {
    int i = blockIdx.x * blockDim.x + threadIdx.x;
    if (i >= n4) return;
    float4 x = ((float4*)out)[i]; float4 y = ((const float4*)b)[i];
    ((float4*)out)[i] = make_float4((x.x + y.x) * s, (x.y + y.y) * s,
                                    (x.z + y.z) * s, (x.w + y.w) * s);
}

extern "C" void kernel_launch(void* const* d_in, const int* in_sizes, int n_in,
                              void* d_out, int out_size, void* d_ws, size_t ws_size,
                              hipStream_t stream) {
    const float* emb  = (const float*)d_in[0];
    const float* vals = (const float*)d_in[1];
    const int*   row  = (const int*)d_in[2];
    const int*   col  = (const int*)d_in[3];
    // num_layers (d_in[4]) fixed at 3 in the reference.

    const int N = in_sizes[0] / DIM;     // 200000
    const int E = in_sizes[1];           // 6.4M
    float* out  = (float*)d_out;

    // ws layout: bufA[N*DIM] f32 | bufB[N*DIM] f32 | count[N] i32 | row_ptr[N] i32 | perm[E] int2
    float* bufA    = (float*)d_ws;
    float* bufB    = bufA + (size_t)N * DIM;
    int*   count   = (int*)(bufB + (size_t)N * DIM);
    int*   row_ptr = count + N;
    int2*  perm    = (int2*)(row_ptr + N);           // byte offset divisible by 8
    const size_t needed = ((size_t)2 * N * DIM + (size_t)2 * N) * 4 + (size_t)E * 8;

    const int n4 = N * DIM / 4;
    const int add_grid = (n4 + 255) / 256;
    const size_t layer_bytes = (size_t)N * DIM * sizeof(float);

    if (ws_size < needed) {
        // fallback: round-1 verified atomic push path
        const int sct_grid = (E + 7) / 8;
        hipMemsetAsync(bufA, 0, layer_bytes, stream);
        lgcn_scatter<<<sct_grid, 256, 0, stream>>>(emb, bufA, vals, row, col, E);
        lgcn_add_init<<<add_grid, 256, 0, stream>>>(emb, bufA, out, n4);
        hipMemsetAsync(bufB, 0, layer_bytes, stream);
        lgcn_scatter<<<sct_grid, 256, 0, stream>>>(bufA, bufB, vals, row, col, E);
        lgcn_add<<<add_grid, 256, 0, stream>>>(bufB, out, n4);
        hipMemsetAsync(bufA, 0, layer_bytes, stream);
        lgcn_scatter<<<sct_grid, 256, 0, stream>>>(bufB, bufA, vals, row, col, E);
        lgcn_add_scale<<<add_grid, 256, 0, stream>>>(bufA, out, n4, 0.25f);
        return;
    }

    // ---- CSR build (no memcpy nodes: memset + kernels only) ----
    hipMemsetAsync(count, 0, (size_t)N * sizeof(int), stream);
    const int e_grid = (E + 255) / 256;
    lgcn_hist<<<e_grid, 256, 0, stream>>>(row, count, E);
    lgcn_scan<<<1, 1024, 0, stream>>>(count, row_ptr, N);
    // permute advances row_ptr[r] to end-of-row-r
    lgcn_permute<<<e_grid, 256, 0, stream>>>(row, col, vals, row_ptr, perm, E);

    // ---- 3 pull layers, fused accumulation (row_ptr now = row-end offsets) ----
    const int pull_grid = (N + 7) / 8;
    lgcn_pull<0><<<pull_grid, 256, 0, stream>>>(row_ptr, perm, emb, bufA, emb, out, N);
    lgcn_pull<1><<<pull_grid, 256, 0, stream>>>(row_ptr, perm, bufA, bufB, emb, out, N);
    lgcn_pull<2><<<pull_grid, 256, 0, stream>>>(row_ptr, perm, bufB, nullptr, emb, out, N);
}

// Round 4
// 671.894 us; speedup vs baseline: 3.0285x; 2.4585x over previous
//
#include <hip/hip_runtime.h>
#include <hip/hip_bf16.h>

#define DIM 32
#define BSHIFT 8            // 256 rows per bucket
#define BROWS 256
#define CAP 12288           // LDS sort capacity (mean 8192 edges/bucket, 45-sigma margin)
#define CHUNK 8192          // edges per bin block
#define KMAX 1024           // max buckets supported (N <= 262144)

// ---------------- bucket build ----------------

// Per-bucket edge counts (bucket = row >> BSHIFT).
__global__ void lgcn_bhist(const int* __restrict__ row,
                           int* __restrict__ bcount, int E, int K) {
    __shared__ int h[KMAX];
    int t = threadIdx.x;
    for (int b = t; b < K; b += blockDim.x) h[b] = 0;
    __syncthreads();
    for (int i = blockIdx.x * blockDim.x + t; i < E; i += gridDim.x * blockDim.x)
        atomicAdd(&h[row[i] >> BSHIFT], 1);
    __syncthreads();
    for (int b = t; b < K; b += blockDim.x)
        if (h[b]) atomicAdd(&bcount[b], h[b]);
}

// Exclusive scan of bucket counts -> bbase[0..K], and bcursor = bbase copy.
__global__ void lgcn_bscan(const int* __restrict__ bcount,
                           int* __restrict__ bbase, int* __restrict__ bcursor, int K) {
    __shared__ int s[1024];
    int t = threadIdx.x;
    int v = (t < K) ? bcount[t] : 0;
    s[t] = v;
    __syncthreads();
    for (int off = 1; off < 1024; off <<= 1) {
        int u = (t >= off) ? s[t - off] : 0;
        __syncthreads();
        s[t] += u;
        __syncthreads();
    }
    if (t < K) {
        int excl = s[t] - v;
        bbase[t] = excl;
        bcursor[t] = excl;
    }
    if (t == 0) bbase[K] = s[1023];
}

// Bin edges into bucket-clustered order. Per block: LDS hist -> reserve
// per-(block,bucket) segments with ONE global atomic per bucket -> clustered
// writes (avg ~84B runs instead of random 8B stores).
__global__ void lgcn_bin(const int* __restrict__ row, const int* __restrict__ col,
                         const float* __restrict__ vals, int* __restrict__ bcursor,
                         int2* __restrict__ binned_cv,
                         unsigned char* __restrict__ binned_row, int E, int K) {
    __shared__ int h[KMAX];
    __shared__ int lrow[CHUNK];
    int t = threadIdx.x;
    for (int b = t; b < K; b += 256) h[b] = 0;
    __syncthreads();
    int base_i = blockIdx.x * CHUNK;
    for (int k = 0; k < CHUNK / 256; ++k) {
        int i = base_i + k * 256 + t;
        int r = (i < E) ? row[i] : -1;
        lrow[k * 256 + t] = r;
        if (r >= 0) atomicAdd(&h[r >> BSHIFT], 1);
    }
    __syncthreads();
    for (int b = t; b < K; b += 256) {
        int c = h[b];
        h[b] = c ? atomicAdd(&bcursor[b], c) : 0;   // h[b] becomes write cursor
    }
    __syncthreads();
    for (int k = 0; k < CHUNK / 256; ++k) {
        int i = base_i + k * 256 + t;
        if (i >= E) break;
        int r = lrow[k * 256 + t];
        int p = atomicAdd(&h[r >> BSHIFT], 1);
        binned_cv[p] = make_int2(col[i], __float_as_int(vals[i]));
        binned_row[p] = (unsigned char)(r & (BROWS - 1));
    }
}

// Per-bucket LDS counting sort (in place): binned -> row-sorted CSR segment.
// Also emits row_end[] (global inclusive end offsets per row).
__global__ void lgcn_bsort(const int* __restrict__ bbase,
                           const unsigned char* __restrict__ binned_row,
                           int2* __restrict__ perm,
                           int* __restrict__ row_end, int N) {
    __shared__ int2 sorted[CAP];
    __shared__ int cnt[BROWS], scn[BROWS], cur[BROWS];
    int b = blockIdx.x, t = threadIdx.x;
    int sB = bbase[b], eB = bbase[b + 1];
    int nB = eB - sB;
    if (t < BROWS) cnt[t] = 0;
    __syncthreads();
    for (int i = sB + t; i < eB; i += 1024)
        atomicAdd(&cnt[binned_row[i]], 1);
    __syncthreads();
    if (t < BROWS) scn[t] = cnt[t];
    __syncthreads();
    for (int off = 1; off < BROWS; off <<= 1) {
        int u = (t >= off && t < BROWS) ? scn[t - off] : 0;
        __syncthreads();
        if (t < BROWS) scn[t] += u;
        __syncthreads();
    }
    int g0 = b << BSHIFT;
    if (t < BROWS) {
        if (g0 + t < N) row_end[g0 + t] = sB + scn[t];   // inclusive end
        cur[t] = scn[t] - cnt[t];                        // local exclusive start
    }
    __syncthreads();
    for (int i = sB + t; i < eB; i += 1024) {
        int r = binned_row[i];
        int p = atomicAdd(&cur[r], 1);
        if (p < CAP) sorted[p] = perm[i];
    }
    __syncthreads();
    for (int p = t; p < nB; p += 1024) {
        int pp = p < CAP ? p : CAP - 1;                  // unreachable clamp
        perm[sB + p] = sorted[pp];
    }
}

// ---------------- pull SpMM, fused layer-sum epilogue ----------------
// MODE 0: e_next = acc; out = emb + acc    (layer 1)
// MODE 1: e_next = acc; out += acc         (layer 2)
// MODE 2: out = (out + acc) * 0.25         (layer 3)
template <int MODE>
__global__ void lgcn_pull(const int* __restrict__ row_end,
                          const int2* __restrict__ perm,
                          const float* __restrict__ e_cur,
                          float* __restrict__ e_next,
                          const float* __restrict__ emb,
                          float* __restrict__ out, int N) {
    int g = blockIdx.x * (blockDim.x >> 5) + (threadIdx.x >> 5);
    if (g >= N) return;
    int d = threadIdx.x & 31;
    int beg = (g == 0) ? 0 : row_end[g - 1];
    int end = row_end[g];
    float acc = 0.f;
    int p = beg;
    for (; p + 3 < end; p += 4) {
        int2 cv0 = perm[p];
        int2 cv1 = perm[p + 1];
        int2 cv2 = perm[p + 2];
        int2 cv3 = perm[p + 3];
        acc = fmaf(__int_as_float(cv0.y), e_cur[(size_t)cv0.x * DIM + d], acc);
        acc = fmaf(__int_as_float(cv1.y), e_cur[(size_t)cv1.x * DIM + d], acc);
        acc = fmaf(__int_as_float(cv2.y), e_cur[(size_t)cv2.x * DIM + d], acc);
        acc = fmaf(__int_as_float(cv3.y), e_cur[(size_t)cv3.x * DIM + d], acc);
    }
    for (; p < end; ++p) {
        int2 cv = perm[p];
        acc = fmaf(__int_as_float(cv.y), e_cur[(size_t)cv.x * DIM + d], acc);
    }
    size_t o = (size_t)g * DIM + d;
    if (MODE == 0)      { e_next[o] = acc; out[o] = emb[o] + acc; }
    else if (MODE == 1) { e_next[o] = acc; out[o] += acc; }
    else                { out[o] = (out[o] + acc) * 0.25f; }
}

// ---------------- fallback (round-1 verified atomic path) ----------------

__global__ void lgcn_scatter(const float* __restrict__ e_cur,
                             float* __restrict__ e_next,
                             const float* __restrict__ vals,
                             const int* __restrict__ row_idx,
                             const int* __restrict__ col_idx, int E) {
    int g = blockIdx.x * (blockDim.x >> 5) + (threadIdx.x >> 5);
    if (g >= E) return;
    int d = threadIdx.x & 31;
    int c = col_idx[g];
    int r = row_idx[g];
    float v = vals[g];
    atomicAdd(&e_next[(size_t)r * DIM + d], v * e_cur[(size_t)c * DIM + d]);
}

__global__ void lgcn_add_init(const float* __restrict__ a, const float* __restrict__ b,
                              float* __restrict__ out, int n4) {
    int i = blockIdx.x * blockDim.x + threadIdx.x;
    if (i >= n4) return;
    float4 x = ((const float4*)a)[i]; float4 y = ((const float4*)b)[i];
    ((float4*)out)[i] = make_float4(x.x + y.x, x.y + y.y, x.z + y.z, x.w + y.w);
}
__global__ void lgcn_add(const float* __restrict__ b, float* __restrict__ out, int n4) {
    int i = blockIdx.x * blockDim.x + threadIdx.x;
    if (i >= n4) return;
    float4 x = ((float4*)out)[i]; float4 y = ((const float4*)b)[i];
    ((float4*)out)[i] = make_float4(x.x + y.x, x.y + y.y, x.z + y.z, x.w + y.w);
}
__global__ void lgcn_add_scale(const float* __restrict__ b, float* __restrict__ out,
                               int n4, float s) {
    int i = blockIdx.x * blockDim.x + threadIdx.x;
    if (i >= n4) return;
    float4 x = ((float4*)out)[i]; float4 y = ((const float4*)b)[i];
    ((float4*)out)[i] = make_float4((x.x + y.x) * s, (x.y + y.y) * s,
                                    (x.z + y.z) * s, (x.w + y.w) * s);
}

extern "C" void kernel_launch(void* const* d_in, const int* in_sizes, int n_in,
                              void* d_out, int out_size, void* d_ws, size_t ws_size,
                              hipStream_t stream) {
    const float* emb  = (const float*)d_in[0];
    const float* vals = (const float*)d_in[1];
    const int*   row  = (const int*)d_in[2];
    const int*   col  = (const int*)d_in[3];
    // num_layers (d_in[4]) fixed at 3 in the reference.

    const int N = in_sizes[0] / DIM;     // 200000
    const int E = in_sizes[1];           // 6.4M
    float* out  = (float*)d_out;

    const int K = (N + BROWS - 1) >> BSHIFT;   // buckets

    // ws layout (4B words):
    //   bufA[N*DIM] | bufB[N*DIM] | row_end[N] | bcount[K] | bbase[K+1] | bcursor[K]
    //   | (8B-align) perm[E] int2
    // binned_row (E bytes) aliases bufA during build.
    float* bufA    = (float*)d_ws;
    float* bufB    = bufA + (size_t)N * DIM;
    int*   row_end = (int*)(bufB + (size_t)N * DIM);
    int*   bcount  = row_end + N;
    int*   bbase   = bcount + K;
    int*   bcursor = bbase + (K + 1);
    size_t word_off = (size_t)((bcursor + K) - (int*)d_ws);
    word_off = (word_off + 1) & ~(size_t)1;            // 8B align
    int2*  perm    = (int2*)((int*)d_ws + word_off);
    unsigned char* rowb8 = (unsigned char*)bufA;       // E bytes <= N*DIM*4
    const size_t needed = (word_off + (size_t)2 * E) * 4;

    const int n4 = N * DIM / 4;
    const int add_grid = (n4 + 255) / 256;
    const size_t layer_bytes = (size_t)N * DIM * sizeof(float);

    // CSR path requires: ws fits, K fits LDS tables, bucket load has margin,
    // row bytes fit in bufA.
    const double mean_bucket = (double)E / (double)N * BROWS;
    const bool csr_ok = (ws_size >= needed) && (K <= KMAX) &&
                        (mean_bucket * 1.45 < (double)CAP) &&
                        ((size_t)E <= (size_t)N * DIM * 4);

    if (!csr_ok) {
        // fallback: round-1 verified atomic push path
        const int sct_grid = (E + 7) / 8;
        hipMemsetAsync(bufA, 0, layer_bytes, stream);
        lgcn_scatter<<<sct_grid, 256, 0, stream>>>(emb, bufA, vals, row, col, E);
        lgcn_add_init<<<add_grid, 256, 0, stream>>>(emb, bufA, out, n4);
        hipMemsetAsync(bufB, 0, layer_bytes, stream);
        lgcn_scatter<<<sct_grid, 256, 0, stream>>>(bufA, bufB, vals, row, col, E);
        lgcn_add<<<add_grid, 256, 0, stream>>>(bufB, out, n4);
        hipMemsetAsync(bufA, 0, layer_bytes, stream);
        lgcn_scatter<<<sct_grid, 256, 0, stream>>>(bufB, bufA, vals, row, col, E);
        lgcn_add_scale<<<add_grid, 256, 0, stream>>>(bufA, out, n4, 0.25f);
        return;
    }

    // ---- bucketed CSR build ----
    const int bin_grid = (E + CHUNK - 1) / CHUNK;
    hipMemsetAsync(bcount, 0, (size_t)K * sizeof(int), stream);
    lgcn_bhist<<<bin_grid, 256, 0, stream>>>(row, bcount, E, K);
    lgcn_bscan<<<1, 1024, 0, stream>>>(bcount, bbase, bcursor, K);
    lgcn_bin<<<bin_grid, 256, 0, stream>>>(row, col, vals, bcursor, perm, rowb8, E, K);
    lgcn_bsort<<<K, 1024, 0, stream>>>(bbase, rowb8, perm, row_end, N);

    // ---- 3 pull layers, fused accumulation ----
    const int pull_grid = (N + 7) / 8;
    lgcn_pull<0><<<pull_grid, 256, 0, stream>>>(row_end, perm, emb, bufA, emb, out, N);
    lgcn_pull<1><<<pull_grid, 256, 0, stream>>>(row_end, perm, bufA, bufB, emb, out, N);
    lgcn_pull<2><<<pull_grid, 256, 0, stream>>>(row_end, perm, bufB, nullptr, emb, out, N);
}

// Round 5
// 539.104 us; speedup vs baseline: 3.7744x; 1.2463x over previous
//
#include <hip/hip_runtime.h>
#include <hip/hip_bf16.h>

#define DIM 32
#define BSHIFT 8            // 256 rows per bucket
#define BROWS 256
#define CAP 12288           // bsort LDS capacity (mean 8192 edges/bucket, 45-sigma margin)
#define CHUNK 8192          // edges per bin block
#define KMAX 1024           // max buckets supported (N <= 262144)

// ---------------- bucket build ----------------

// Per-bucket edge counts (bucket = row >> BSHIFT).
__global__ void lgcn_bhist(const int* __restrict__ row,
                           int* __restrict__ bcount, int E, int K) {
    __shared__ int h[KMAX];
    int t = threadIdx.x;
    for (int b = t; b < K; b += blockDim.x) h[b] = 0;
    __syncthreads();
    for (int i = blockIdx.x * blockDim.x + t; i < E; i += gridDim.x * blockDim.x)
        atomicAdd(&h[row[i] >> BSHIFT], 1);
    __syncthreads();
    for (int b = t; b < K; b += blockDim.x)
        if (h[b]) atomicAdd(&bcount[b], h[b]);
}

// Exclusive scan of bucket counts -> bbase[0..K], and bcursor = bbase copy.
__global__ void lgcn_bscan(const int* __restrict__ bcount,
                           int* __restrict__ bbase, int* __restrict__ bcursor, int K) {
    __shared__ int s[1024];
    int t = threadIdx.x;
    int v = (t < K) ? bcount[t] : 0;
    s[t] = v;
    __syncthreads();
    for (int off = 1; off < 1024; off <<= 1) {
        int u = (t >= off) ? s[t - off] : 0;
        __syncthreads();
        s[t] += u;
        __syncthreads();
    }
    if (t < K) {
        int excl = s[t] - v;
        bbase[t] = excl;
        bcursor[t] = excl;
    }
    if (t == 0) bbase[K] = s[1023];
}

// Bin edges into bucket-clustered order, LDS-sorted per chunk so global writes
// are issued contiguous-in-time per bucket segment (full-line writebacks).
// Packs rowlow into cv.x's top byte (requires N < 2^24).
__launch_bounds__(1024)
__global__ void lgcn_bin(const int* __restrict__ row, const int* __restrict__ col,
                         const float* __restrict__ vals, int* __restrict__ bcursor,
                         int2* __restrict__ binned, int E, int K) {
    __shared__ int hh[KMAX];       // count -> gdelta (gbase - local_excl_base)
    __shared__ int lb[KMAX + 1];   // scan buffer -> local exclusive bases
    __shared__ int cur[KMAX];      // LDS scatter cursors
    __shared__ int2 sbuf[CHUNK];   // 64 KB bucket-sorted chunk
    int t = threadIdx.x;
    int base = blockIdx.x * CHUNK;
    int cnt = E - base;
    if (cnt > CHUNK) cnt = CHUNK;

    for (int b = t; b < K; b += 1024) hh[b] = 0;
    __syncthreads();

    int  myb[CHUNK / 1024];
    int2 mycv[CHUNK / 1024];
    for (int k = 0; k < CHUNK / 1024; ++k) {
        int i = base + k * 1024 + t;
        if (i < base + cnt) {
            int r = row[i];
            myb[k] = r >> BSHIFT;
            mycv[k] = make_int2(col[i] | ((r & (BROWS - 1)) << 24),
                                __float_as_int(vals[i]));
            atomicAdd(&hh[myb[k]], 1);
        } else myb[k] = -1;
    }
    __syncthreads();

    // inclusive scan of hh over 1024 slots (hh[b>=K] == 0)
    int v = (t < K) ? hh[t] : 0;
    lb[t] = v;
    __syncthreads();
    for (int off = 1; off < 1024; off <<= 1) {
        int u = (t >= off) ? lb[t - off] : 0;
        __syncthreads();
        lb[t] += u;
        __syncthreads();
    }
    if (t == 0) lb[K] = cnt;
    int excl = lb[t] - v;          // local exclusive base for bucket t
    __syncthreads();
    if (t < K) {
        lb[t] = excl;
        cur[t] = excl;
        int gbase = v ? atomicAdd(&bcursor[t], v) : 0;
        hh[t] = gbase - excl;      // gdelta
    }
    __syncthreads();

    // scatter into LDS bucket-sorted order
    for (int k = 0; k < CHUNK / 1024; ++k) {
        if (myb[k] >= 0) {
            int pos = atomicAdd(&cur[myb[k]], 1);
            sbuf[pos] = mycv[k];
        }
    }
    __syncthreads();

    // ordered write-out: consecutive p -> consecutive global within each segment
    for (int p = t; p < cnt; p += 1024) {
        int lo = 0, hi = K;        // invariant: lb[lo] <= p < lb[hi]
        while (hi - lo > 1) {
            int mid = (lo + hi) >> 1;
            if (lb[mid] <= p) lo = mid; else hi = mid;
        }
        binned[hh[lo] + p] = sbuf[p];
    }
}

// Per-bucket LDS counting sort (in place): binned -> row-sorted CSR segment.
// Strips the packed rowlow byte. Emits row_end[] (inclusive end offsets).
__global__ void lgcn_bsort(const int* __restrict__ bbase,
                           int2* __restrict__ perm,
                           int* __restrict__ row_end, int N) {
    __shared__ int2 sorted[CAP];
    __shared__ int cnt[BROWS], scn[BROWS], cur[BROWS];
    int b = blockIdx.x, t = threadIdx.x;
    int sB = bbase[b], eB = bbase[b + 1];
    int nB = eB - sB;
    if (t < BROWS) cnt[t] = 0;
    __syncthreads();
    for (int i = sB + t; i < eB; i += 1024)
        atomicAdd(&cnt[(unsigned)perm[i].x >> 24], 1);
    __syncthreads();
    if (t < BROWS) scn[t] = cnt[t];
    __syncthreads();
    for (int off = 1; off < BROWS; off <<= 1) {
        int u = (t >= off && t < BROWS) ? scn[t - off] : 0;
        __syncthreads();
        if (t < BROWS) scn[t] += u;
        __syncthreads();
    }
    int g0 = b << BSHIFT;
    if (t < BROWS) {
        if (g0 + t < N) row_end[g0 + t] = sB + scn[t];   // inclusive end
        cur[t] = scn[t] - cnt[t];                        // local exclusive start
    }
    __syncthreads();
    for (int i = sB + t; i < eB; i += 1024) {
        int2 cv = perm[i];
        int r = (unsigned)cv.x >> 24;
        int p = atomicAdd(&cur[r], 1);
        if (p < CAP) sorted[p] = cv;
    }
    __syncthreads();
    for (int p = t; p < nB; p += 1024) {
        int pp = p < CAP ? p : CAP - 1;                  // unreachable clamp
        int2 cv = sorted[pp];
        perm[sB + p] = make_int2(cv.x & 0x00FFFFFF, cv.y);
    }
}

// ---------------- pull SpMM, fused layer-sum epilogue ----------------
// MODE 0: e_next = acc; out = emb + acc    (layer 1)
// MODE 1: e_next = acc; out += acc         (layer 2)
// MODE 2: out = (out + acc) * 0.25         (layer 3)
template <int MODE>
__global__ void lgcn_pull(const int* __restrict__ row_end,
                          const int2* __restrict__ perm,
                          const float* __restrict__ e_cur,
                          float* __restrict__ e_next,
                          const float* __restrict__ emb,
                          float* __restrict__ out, int N) {
    int g = blockIdx.x * (blockDim.x >> 5) + (threadIdx.x >> 5);
    if (g >= N) return;
    int d = threadIdx.x & 31;
    int beg = (g == 0) ? 0 : row_end[g - 1];
    int end = row_end[g];
    float acc = 0.f;
    int p = beg;
    for (; p + 3 < end; p += 4) {
        int2 cv0 = perm[p];
        int2 cv1 = perm[p + 1];
        int2 cv2 = perm[p + 2];
        int2 cv3 = perm[p + 3];
        acc = fmaf(__int_as_float(cv0.y), e_cur[(size_t)cv0.x * DIM + d], acc);
        acc = fmaf(__int_as_float(cv1.y), e_cur[(size_t)cv1.x * DIM + d], acc);
        acc = fmaf(__int_as_float(cv2.y), e_cur[(size_t)cv2.x * DIM + d], acc);
        acc = fmaf(__int_as_float(cv3.y), e_cur[(size_t)cv3.x * DIM + d], acc);
    }
    for (; p < end; ++p) {
        int2 cv = perm[p];
        acc = fmaf(__int_as_float(cv.y), e_cur[(size_t)cv.x * DIM + d], acc);
    }
    size_t o = (size_t)g * DIM + d;
    if (MODE == 0)      { e_next[o] = acc; out[o] = emb[o] + acc; }
    else if (MODE == 1) { e_next[o] = acc; out[o] += acc; }
    else                { out[o] = (out[o] + acc) * 0.25f; }
}

// ---------------- fallback (round-1 verified atomic path) ----------------

__global__ void lgcn_scatter(const float* __restrict__ e_cur,
                             float* __restrict__ e_next,
                             const float* __restrict__ vals,
                             const int* __restrict__ row_idx,
                             const int* __restrict__ col_idx, int E) {
    int g = blockIdx.x * (blockDim.x >> 5) + (threadIdx.x >> 5);
    if (g >= E) return;
    int d = threadIdx.x & 31;
    int c = col_idx[g];
    int r = row_idx[g];
    float v = vals[g];
    atomicAdd(&e_next[(size_t)r * DIM + d], v * e_cur[(size_t)c * DIM + d]);
}

__global__ void lgcn_add_init(const float* __restrict__ a, const float* __restrict__ b,
                              float* __restrict__ out, int n4) {
    int i = blockIdx.x * blockDim.x + threadIdx.x;
    if (i >= n4) return;
    float4 x = ((const float4*)a)[i]; float4 y = ((const float4*)b)[i];
    ((float4*)out)[i] = make_float4(x.x + y.x, x.y + y.y, x.z + y.z, x.w + y.w);
}
__global__ void lgcn_add(const float* __restrict__ b, float* __restrict__ out, int n4) {
    int i = blockIdx.x * blockDim.x + threadIdx.x;
    if (i >= n4) return;
    float4 x = ((float4*)out)[i]; float4 y = ((const float4*)b)[i];
    ((float4*)out)[i] = make_float4(x.x + y.x, x.y + y.y, x.z + y.z, x.w + y.w);
}
__global__ void lgcn_add_scale(const float* __restrict__ b, float* __restrict__ out,
                               int n4, float s) {
    int i = blockIdx.x * blockDim.x + threadIdx.x;
    if (i >= n4) return;
    float4 x = ((float4*)out)[i]; float4 y = ((const float4*)b)[i];
    ((float4*)out)[i] = make_float4((x.x + y.x) * s, (x.y + y.y) * s,
                                    (x.z + y.z) * s, (x.w + y.w) * s);
}

extern "C" void kernel_launch(void* const* d_in, const int* in_sizes, int n_in,
                              void* d_out, int out_size, void* d_ws, size_t ws_size,
                              hipStream_t stream) {
    const float* emb  = (const float*)d_in[0];
    const float* vals = (const float*)d_in[1];
    const int*   row  = (const int*)d_in[2];
    const int*   col  = (const int*)d_in[3];
    // num_layers (d_in[4]) fixed at 3 in the reference.

    const int N = in_sizes[0] / DIM;     // 200000
    const int E = in_sizes[1];           // 6.4M
    float* out  = (float*)d_out;

    const int K = (N + BROWS - 1) >> BSHIFT;   // buckets

    // ws layout (4B words):
    //   bufA[N*DIM] | bufB[N*DIM] | row_end[N] | bcount[K] | bbase[K+1] | bcursor[K]
    //   | (8B-align) perm[E] int2
    float* bufA    = (float*)d_ws;
    float* bufB    = bufA + (size_t)N * DIM;
    int*   row_end = (int*)(bufB + (size_t)N * DIM);
    int*   bcount  = row_end + N;
    int*   bbase   = bcount + K;
    int*   bcursor = bbase + (K + 1);
    size_t word_off = (size_t)((bcursor + K) - (int*)d_ws);
    word_off = (word_off + 1) & ~(size_t)1;            // 8B align
    int2*  perm    = (int2*)((int*)d_ws + word_off);
    const size_t needed = (word_off + (size_t)2 * E) * 4;

    const int n4 = N * DIM / 4;
    const int add_grid = (n4 + 255) / 256;
    const size_t layer_bytes = (size_t)N * DIM * sizeof(float);

    // CSR path requires: ws fits, K fits LDS tables, bucket load margin,
    // col fits 24 bits for rowlow packing.
    const double mean_bucket = (double)E / (double)N * BROWS;
    const bool csr_ok = (ws_size >= needed) && (K <= KMAX) &&
                        (mean_bucket * 1.45 < (double)CAP) &&
                        (N < (1 << 24));

    if (!csr_ok) {
        // fallback: round-1 verified atomic push path
        const int sct_grid = (E + 7) / 8;
        hipMemsetAsync(bufA, 0, layer_bytes, stream);
        lgcn_scatter<<<sct_grid, 256, 0, stream>>>(emb, bufA, vals, row, col, E);
        lgcn_add_init<<<add_grid, 256, 0, stream>>>(emb, bufA, out, n4);
        hipMemsetAsync(bufB, 0, layer_bytes, stream);
        lgcn_scatter<<<sct_grid, 256, 0, stream>>>(bufA, bufB, vals, row, col, E);
        lgcn_add<<<add_grid, 256, 0, stream>>>(bufB, out, n4);
        hipMemsetAsync(bufA, 0, layer_bytes, stream);
        lgcn_scatter<<<sct_grid, 256, 0, stream>>>(bufB, bufA, vals, row, col, E);
        lgcn_add_scale<<<add_grid, 256, 0, stream>>>(bufA, out, n4, 0.25f);
        return;
    }

    // ---- bucketed CSR build ----
    const int bin_grid = (E + CHUNK - 1) / CHUNK;
    hipMemsetAsync(bcount, 0, (size_t)K * sizeof(int), stream);
    lgcn_bhist<<<bin_grid, 256, 0, stream>>>(row, bcount, E, K);
    lgcn_bscan<<<1, 1024, 0, stream>>>(bcount, bbase, bcursor, K);
    lgcn_bin<<<bin_grid, 1024, 0, stream>>>(row, col, vals, bcursor, perm, E, K);
    lgcn_bsort<<<K, 1024, 0, stream>>>(bbase, perm, row_end, N);

    // ---- 3 pull layers, fused accumulation ----
    const int pull_grid = (N + 7) / 8;
    lgcn_pull<0><<<pull_grid, 256, 0, stream>>>(row_end, perm, emb, bufA, emb, out, N);
    lgcn_pull<1><<<pull_grid, 256, 0, stream>>>(row_end, perm, bufA, bufB, emb, out, N);
    lgcn_pull<2><<<pull_grid, 256, 0, stream>>>(row_end, perm, bufB, nullptr, emb, out, N);
}